// Round 4
// baseline (158.935 us; speedup 1.0000x reference)
//
#include <hip/hip_runtime.h>

#define B_DIM   2048
#define IN_DIM  4096
#define OUT_DIM 4096
#define FAN     64

// R9: intra-block double-buffer inside a 32 KB LDS footprint.
//  - 2-ROW tiles: cell (t,c) = 4 B = bf16{x[2t,c], x[2t+1,c]}; tile = 16 KB
//    spanning all 4096 cols (irreducible: mask indexes any col).
//  - two 16 KB buffers, R5's proven A/B pipeline: prefetch next tile into the
//    spare buffer (global_load_lds w=16) while gathering current with
//    ds_read_b32; buffer parity = compile-time +16384 on the same address
//    regs (zero extra VALU).
//  - 256 threads, plain __launch_bounds__(256): R6/R7 showed the 2nd arg acts
//    as min-WG/CU (VGPR cap 64 at ",4" -> spill); R5/R8's ",2" correlates with
//    8-wave/CU residency (Occupancy 19% both). Drop the hint; allocator lands
//    ~108 VGPR naturally.
//  - grid (64,16) = 1024 blocks; 32 rows (16 tiles) per block.
// R8 post-mortem: 55.3 us at ~56% LDS-pipe util, occupancy stuck at 19% ->
// exposed per-tile DMA drain; this round hides it inside the block.

typedef float v2f __attribute__((ext_vector_type(2)));

__device__ __forceinline__ unsigned bf16_rne(float f) {
    unsigned u = __float_as_uint(f);
    return (u + 0x7fffu + ((u >> 16) & 1u)) >> 16;   // round-to-nearest-even bf16
}

// ---------------- Phase 1: pack fp32 -> bf16 2-row cells ----------------
// Tile t = rows {2t, 2t+1}; wsp uint index t*4096 + c; cell lo = row 2t,
// hi = row 2t+1. One thread packs 4 consecutive cols (one uint4).
__global__ __launch_bounds__(256) void pack_kernel(
    const float* __restrict__ input, uint4* __restrict__ wsp)
{
    const int idx = blockIdx.x * 256 + threadIdx.x;   // [0, 1048576) quad-cells
    const int t   = idx >> 10;                        // tile [0,1024)
    const int c0  = (idx & 1023) << 2;                // col base (4 cols)

    const float* p = input + (size_t)t * 2 * IN_DIM + c0;
    const float4 r0 = *reinterpret_cast<const float4*>(p);
    const float4 r1 = *reinterpret_cast<const float4*>(p + IN_DIM);

    uint4 q;
    q.x = bf16_rne(r0.x) | (bf16_rne(r1.x) << 16);
    q.y = bf16_rne(r0.y) | (bf16_rne(r1.y) << 16);
    q.z = bf16_rne(r0.z) | (bf16_rne(r1.z) << 16);
    q.w = bf16_rne(r0.w) | (bf16_rne(r1.w) << 16);

    wsp[idx] = q;
}

// ---------------- Phase 2: pipelined gather + accumulate ----------------
__global__ __launch_bounds__(256) void condensed_kernel(
    const uint4* __restrict__ wsp,
    const float* __restrict__ weight,
    const float* __restrict__ bias,
    const int*   __restrict__ mask,
    float*       __restrict__ out)
{
    __shared__ __align__(16) uint4 lds[2048];         // 32 KB = 2 x 16 KB buffers

    const int tid     = threadIdx.x;
    const int o       = blockIdx.y * 256 + tid;
    const int tbase   = blockIdx.x * 16;              // 16 tiles of 2 rows
    const int rowbase = blockIdx.x * 32;              // 32 batch rows per block

    // ---- idx -> LDS byte addresses (cell = 4 B) + weights, in registers ----
    unsigned addrs[FAN];
    float    wv[FAN];
    {
        const int4*   mv = reinterpret_cast<const int4*>(mask)     + o * (FAN / 4);
        const float4* wp = reinterpret_cast<const float4*>(weight) + o * (FAN / 4);
        #pragma unroll
        for (int j = 0; j < FAN / 4; ++j) {
            int4   m4 = mv[j];
            float4 w4 = wp[j];
            addrs[4*j+0] = (unsigned)m4.x << 2;
            addrs[4*j+1] = (unsigned)m4.y << 2;
            addrs[4*j+2] = (unsigned)m4.z << 2;
            addrs[4*j+3] = (unsigned)m4.w << 2;
            wv[4*j+0] = w4.x;
            wv[4*j+1] = w4.y;
            wv[4*j+2] = w4.z;
            wv[4*j+3] = w4.w;
        }
    }
    const float bv = bias[o];

    // ---- prologue: DMA tile tbase -> buf0 (16 KB = 4 x 16 B per thread) ----
    {
        const uint4* src = wsp + (size_t)tbase * 1024 + tid;
        #pragma unroll
        for (int it = 0; it < 4; ++it) {
            __builtin_amdgcn_global_load_lds(
                (const __attribute__((address_space(1))) unsigned*)(src + it * 256),
                (__attribute__((address_space(3))) unsigned*)(lds + it * 256 + tid),
                16, 0, 0);
        }
    }
    __syncthreads();

    const char* ldsb = reinterpret_cast<const char*>(lds);

    for (int hp = 0; hp < 8; ++hp) {
        // ==== stage A: prefetch tile 2hp+1 -> buf1, compute buf0 (offset 0) ====
        {
            const uint4* src = wsp + (size_t)(tbase + 2 * hp + 1) * 1024 + tid;
            #pragma unroll
            for (int it = 0; it < 4; ++it) {
                __builtin_amdgcn_global_load_lds(
                    (const __attribute__((address_space(1))) unsigned*)(src + it * 256),
                    (__attribute__((address_space(3))) unsigned*)(lds + 1024 + it * 256 + tid),
                    16, 0, 0);
            }
        }
        {
            v2f a01 = {0.f, 0.f};
            #pragma unroll
            for (int j = 0; j < FAN; ++j) {
                const unsigned g = *reinterpret_cast<const unsigned*>(ldsb + addrs[j]);
                const v2f w2 = {wv[j], wv[j]};
                v2f v;
                v.x = __uint_as_float(g << 16);
                v.y = __uint_as_float(g & 0xffff0000u);
                a01 = __builtin_elementwise_fma(v, w2, a01);
            }
            float* op = out + (size_t)(rowbase + 4 * hp) * OUT_DIM + o;
            op[0 * OUT_DIM] = a01.x + bv;
            op[1 * OUT_DIM] = a01.y + bv;
        }
        __syncthreads();   // buf0 free; DMA(-> buf1) drained

        // ==== stage B: prefetch tile 2hp+2 -> buf0, compute buf1 (+16384) ====
        if (hp < 7) {
            const uint4* src = wsp + (size_t)(tbase + 2 * hp + 2) * 1024 + tid;
            #pragma unroll
            for (int it = 0; it < 4; ++it) {
                __builtin_amdgcn_global_load_lds(
                    (const __attribute__((address_space(1))) unsigned*)(src + it * 256),
                    (__attribute__((address_space(3))) unsigned*)(lds + it * 256 + tid),
                    16, 0, 0);
            }
        }
        {
            v2f a01 = {0.f, 0.f};
            #pragma unroll
            for (int j = 0; j < FAN; ++j) {
                // +16384 = buf1; folds into the ds_read offset field
                const unsigned g = *reinterpret_cast<const unsigned*>(ldsb + 16384 + addrs[j]);
                const v2f w2 = {wv[j], wv[j]};
                v2f v;
                v.x = __uint_as_float(g << 16);
                v.y = __uint_as_float(g & 0xffff0000u);
                a01 = __builtin_elementwise_fma(v, w2, a01);
            }
            float* op = out + (size_t)(rowbase + 4 * hp + 2) * OUT_DIM + o;
            op[0 * OUT_DIM] = a01.x + bv;
            op[1 * OUT_DIM] = a01.y + bv;
        }
        __syncthreads();   // buf1 free; DMA(-> buf0) drained
    }
}

extern "C" void kernel_launch(void* const* d_in, const int* in_sizes, int n_in,
                              void* d_out, int out_size, void* d_ws, size_t ws_size,
                              hipStream_t stream) {
    const float* input  = (const float*)d_in[0];
    const float* weight = (const float*)d_in[1];
    const float* bias   = (const float*)d_in[2];
    const int*   mask   = (const int*)d_in[3];
    float*       out    = (float*)d_out;
    uint4*       wsp    = (uint4*)d_ws;               // needs 16 MiB

    pack_kernel<<<4096, 256, 0, stream>>>(input, wsp);
    dim3 grid(64, 16);  // 1024 blocks, 32 KB LDS each
    condensed_kernel<<<grid, 256, 0, stream>>>(wsp, weight, bias, mask, out);
}

// Round 5
// 133.399 us; speedup vs baseline: 1.1914x; 1.1914x over previous
//
#include <hip/hip_runtime.h>

#define B_DIM   2048
#define IN_DIM  4096
#define OUT_DIM 4096
#define FAN     64

// R10: R9's proven pipeline structure (intra-block double-buffer, compile-time
// buffer parity, small phases -> ~94% LDS-pipe busy) x R6's proven op mix
// (8-row 16B cells, ds_read_b128 -> lowest base+conflict cycles: 4096 ops/CU
// x ~12cyc + 33.6k conflict ~= 82k cyc/CU ~= 34us), WITHOUT R6's spill:
//  - 512-thread blocks, __launch_bounds__(512, 1). Empirical decode of the
//    2nd arg: it acts as min WORKGROUPS/CU ((512,4)->cap 64 VGPR-> spill;
//    (256,2)->cap 256 -> healthy 112). (512,1) -> 8 waves/CU -> cap 256:
//    zero spill risk. LDS (128 KB) limits residency to 1 block/CU anyway.
//  - grid (32, 8) = 256 blocks = exactly 1/CU; 64 rows (8 tiles) per block.
//  - per phase: DMA next 64 KB tile into spare buffer (global_load_lds w=16)
//    while gathering current with ds_read_b128 (+65536 parity offset folds
//    into the ds_read offset field).
// Conflict model lesson (R9): extra cycles/wave-op is ~constant (~5-8) across
// widths -> fewest, widest ops win. b32 doubled total conflict cycles.

typedef float v2f __attribute__((ext_vector_type(2)));

__device__ __forceinline__ unsigned bf16_rne(float f) {
    unsigned u = __float_as_uint(f);
    return (u + 0x7fffu + ((u >> 16) & 1u)) >> 16;   // round-to-nearest-even bf16
}

// ---------------- Phase 1: pack fp32 -> bf16 8-row cells ----------------
// Tile t = rows 8t..8t+7 (256 tiles); cell (t,c) = 16 B at wsp[t*4096 + c]:
// dw0 = bf16 rows(0,1), dw1 = rows(2,3), dw2 = rows(4,5), dw3 = rows(6,7).
__global__ __launch_bounds__(256) void pack_kernel(
    const float* __restrict__ input, uint4* __restrict__ wsp)
{
    const int idx = blockIdx.x * 256 + threadIdx.x;   // [0, 524288) cell-pairs
    const int t   = idx >> 11;                        // tile [0,256)
    const int c0  = (idx & 2047) << 1;                // column pair base

    const float* p = input + (size_t)t * 8 * IN_DIM + c0;
    float2 r[8];
    #pragma unroll
    for (int i = 0; i < 8; ++i)
        r[i] = *reinterpret_cast<const float2*>(p + i * IN_DIM);

    uint4 q0, q1;                                     // cells c0 and c0+1
    q0.x = bf16_rne(r[0].x) | (bf16_rne(r[1].x) << 16);
    q0.y = bf16_rne(r[2].x) | (bf16_rne(r[3].x) << 16);
    q0.z = bf16_rne(r[4].x) | (bf16_rne(r[5].x) << 16);
    q0.w = bf16_rne(r[6].x) | (bf16_rne(r[7].x) << 16);
    q1.x = bf16_rne(r[0].y) | (bf16_rne(r[1].y) << 16);
    q1.y = bf16_rne(r[2].y) | (bf16_rne(r[3].y) << 16);
    q1.z = bf16_rne(r[4].y) | (bf16_rne(r[5].y) << 16);
    q1.w = bf16_rne(r[6].y) | (bf16_rne(r[7].y) << 16);

    wsp[(size_t)t * 4096 + c0 + 0] = q0;
    wsp[(size_t)t * 4096 + c0 + 1] = q1;
}

// ---------------- Phase 2: pipelined gather + accumulate ----------------
__global__ __launch_bounds__(512, 1) void condensed_kernel(
    const uint4* __restrict__ wsp,
    const float* __restrict__ weight,
    const float* __restrict__ bias,
    const int*   __restrict__ mask,
    float*       __restrict__ out)
{
    __shared__ __align__(16) uint4 lds[8192];         // 128 KB = 2 x 64 KB buffers

    const int tid     = threadIdx.x;
    const int o       = blockIdx.y * 512 + tid;
    const int tbase   = blockIdx.x * 8;               // 8 tiles of 8 rows
    const int rowbase = blockIdx.x * 64;              // 64 batch rows per block

    // ---- idx -> LDS byte addresses (cell = 16 B) + weights, in registers ----
    unsigned addrs[FAN];
    float    wv[FAN];
    {
        const int4*   mv = reinterpret_cast<const int4*>(mask)     + o * (FAN / 4);
        const float4* wp = reinterpret_cast<const float4*>(weight) + o * (FAN / 4);
        #pragma unroll
        for (int j = 0; j < FAN / 4; ++j) {
            int4   m4 = mv[j];
            float4 w4 = wp[j];
            addrs[4*j+0] = (unsigned)m4.x << 4;
            addrs[4*j+1] = (unsigned)m4.y << 4;
            addrs[4*j+2] = (unsigned)m4.z << 4;
            addrs[4*j+3] = (unsigned)m4.w << 4;
            wv[4*j+0] = w4.x;
            wv[4*j+1] = w4.y;
            wv[4*j+2] = w4.z;
            wv[4*j+3] = w4.w;
        }
    }
    const float bv = bias[o];

    // ---- prologue: DMA tile tbase -> buf0 (64 KB = 8 x 16 B per thread) ----
    {
        const uint4* src = wsp + (size_t)tbase * 4096 + tid;
        #pragma unroll
        for (int it = 0; it < 8; ++it) {
            __builtin_amdgcn_global_load_lds(
                (const __attribute__((address_space(1))) unsigned*)(src + it * 512),
                (__attribute__((address_space(3))) unsigned*)(lds + it * 512 + tid),
                16, 0, 0);
        }
    }
    __syncthreads();

    const char* ldsb = reinterpret_cast<const char*>(lds);

    for (int hp = 0; hp < 4; ++hp) {
        // ==== stage A: prefetch tile 2hp+1 -> buf1, compute buf0 (offset 0) ====
        {
            const uint4* src = wsp + (size_t)(tbase + 2 * hp + 1) * 4096 + tid;
            #pragma unroll
            for (int it = 0; it < 8; ++it) {
                __builtin_amdgcn_global_load_lds(
                    (const __attribute__((address_space(1))) unsigned*)(src + it * 512),
                    (__attribute__((address_space(3))) unsigned*)(lds + 4096 + it * 512 + tid),
                    16, 0, 0);
            }
        }
        {
            v2f a01 = {0.f, 0.f}, a23 = {0.f, 0.f}, a45 = {0.f, 0.f}, a67 = {0.f, 0.f};
            #pragma unroll
            for (int j = 0; j < FAN; ++j) {
                const uint4 g = *reinterpret_cast<const uint4*>(ldsb + addrs[j]);
                const v2f w2 = {wv[j], wv[j]};
                v2f v;
                v.x = __uint_as_float(g.x << 16);
                v.y = __uint_as_float(g.x & 0xffff0000u);
                a01 = __builtin_elementwise_fma(v, w2, a01);
                v.x = __uint_as_float(g.y << 16);
                v.y = __uint_as_float(g.y & 0xffff0000u);
                a23 = __builtin_elementwise_fma(v, w2, a23);
                v.x = __uint_as_float(g.z << 16);
                v.y = __uint_as_float(g.z & 0xffff0000u);
                a45 = __builtin_elementwise_fma(v, w2, a45);
                v.x = __uint_as_float(g.w << 16);
                v.y = __uint_as_float(g.w & 0xffff0000u);
                a67 = __builtin_elementwise_fma(v, w2, a67);
            }
            float* op = out + (size_t)(rowbase + 8 * (2 * hp)) * OUT_DIM + o;
            op[0 * OUT_DIM] = a01.x + bv;
            op[1 * OUT_DIM] = a01.y + bv;
            op[2 * OUT_DIM] = a23.x + bv;
            op[3 * OUT_DIM] = a23.y + bv;
            op[4 * OUT_DIM] = a45.x + bv;
            op[5 * OUT_DIM] = a45.y + bv;
            op[6 * OUT_DIM] = a67.x + bv;
            op[7 * OUT_DIM] = a67.y + bv;
        }
        __syncthreads();   // buf0 free; DMA(-> buf1) drained

        // ==== stage B: prefetch tile 2hp+2 -> buf0, compute buf1 (+65536) ====
        if (hp < 3) {
            const uint4* src = wsp + (size_t)(tbase + 2 * hp + 2) * 4096 + tid;
            #pragma unroll
            for (int it = 0; it < 8; ++it) {
                __builtin_amdgcn_global_load_lds(
                    (const __attribute__((address_space(1))) unsigned*)(src + it * 512),
                    (__attribute__((address_space(3))) unsigned*)(lds + it * 512 + tid),
                    16, 0, 0);
            }
        }
        {
            v2f a01 = {0.f, 0.f}, a23 = {0.f, 0.f}, a45 = {0.f, 0.f}, a67 = {0.f, 0.f};
            #pragma unroll
            for (int j = 0; j < FAN; ++j) {
                // +65536 = buf1; compile-time constant folds into ds_read offset
                const uint4 g = *reinterpret_cast<const uint4*>(ldsb + 65536 + addrs[j]);
                const v2f w2 = {wv[j], wv[j]};
                v2f v;
                v.x = __uint_as_float(g.x << 16);
                v.y = __uint_as_float(g.x & 0xffff0000u);
                a01 = __builtin_elementwise_fma(v, w2, a01);
                v.x = __uint_as_float(g.y << 16);
                v.y = __uint_as_float(g.y & 0xffff0000u);
                a23 = __builtin_elementwise_fma(v, w2, a23);
                v.x = __uint_as_float(g.z << 16);
                v.y = __uint_as_float(g.z & 0xffff0000u);
                a45 = __builtin_elementwise_fma(v, w2, a45);
                v.x = __uint_as_float(g.w << 16);
                v.y = __uint_as_float(g.w & 0xffff0000u);
                a67 = __builtin_elementwise_fma(v, w2, a67);
            }
            float* op = out + (size_t)(rowbase + 8 * (2 * hp + 1)) * OUT_DIM + o;
            op[0 * OUT_DIM] = a01.x + bv;
            op[1 * OUT_DIM] = a01.y + bv;
            op[2 * OUT_DIM] = a23.x + bv;
            op[3 * OUT_DIM] = a23.y + bv;
            op[4 * OUT_DIM] = a45.x + bv;
            op[5 * OUT_DIM] = a45.y + bv;
            op[6 * OUT_DIM] = a67.x + bv;
            op[7 * OUT_DIM] = a67.y + bv;
        }
        __syncthreads();   // buf1 free; DMA(-> buf0) drained
    }
}

extern "C" void kernel_launch(void* const* d_in, const int* in_sizes, int n_in,
                              void* d_out, int out_size, void* d_ws, size_t ws_size,
                              hipStream_t stream) {
    const float* input  = (const float*)d_in[0];
    const float* weight = (const float*)d_in[1];
    const float* bias   = (const float*)d_in[2];
    const int*   mask   = (const int*)d_in[3];
    float*       out    = (float*)d_out;
    uint4*       wsp    = (uint4*)d_ws;               // needs 16 MiB

    pack_kernel<<<2048, 256, 0, stream>>>(input, wsp);
    dim3 grid(32, 8);   // 256 blocks = exactly 1/CU (128 KB LDS, 512 threads)
    condensed_kernel<<<grid, 512, 0, stream>>>(wsp, weight, bias, mask, out);
}